// Round 4
// baseline (381.398 us; speedup 1.0000x reference)
//
#include <hip/hip_runtime.h>
#include <stdint.h>

// ---------------------------------------------------------------------------
// SelfAttention (B=4, C=512, N=4096, A=512), softmax over QUERY axis (n).
// All-fp16 MFMA pipeline, z-batched, m97-style global_load_lds staging:
//   prep:   weights -> fp16; x[b][c][n] -> xT[b][n][c] fp16
//   projQK: QK[z][n][0:512]=Q+bq, [512:1024]=K+bk          (fp16)
//   projV:  Vt[z][c][m] = Wv·x + bv                         (fp16)
//   scores: S~[z][n][m] = fp16 exp(s - tile_max) + per-tile col stats
//   stats_final -> lse[z][m]; scale_factors -> fs16[z][tile][m] (fp16)
//   gemm3:  out[z][n][c] = x.flat + 0.1 * sum_m (S~[n][m]*fs16[tile(n)][m]) Vt[c][m]
//           fs16 applied POST-LDS-read (per-k scale) so A/B both DMA-stage.
// ---------------------------------------------------------------------------

typedef _Float16 f16x8 __attribute__((ext_vector_type(8)));
typedef float f32x4 __attribute__((ext_vector_type(4)));

__device__ __forceinline__ void dma16(const void* g, void* l) {
  __builtin_amdgcn_global_load_lds(
      (const __attribute__((address_space(1))) uint32_t*)(uintptr_t)g,
      (__attribute__((address_space(3))) uint32_t*)(uint32_t)(uintptr_t)l, 16, 0, 0);
}

__device__ __forceinline__ uint16_t f2bf(float f) {
  uint32_t u = __float_as_uint(f);
  u += 0x7FFFu + ((u >> 16) & 1u);
  return (uint16_t)(u >> 16);
}

// ASRC: 0 = plain A; 1 = A scaled post-LDS-read by fs16[z][i0>>7][k] (gemm3)
// EPI:  1 = fp16 out + bias by col (bias0 j<512, bias1 else)  [projQK]
//       2 = fp16 out + bias by row (bias0)                     [projV]
//       3 = fp32 out = xadd[o] + alpha*acc                     [gemm3]
//       4 = fused scores: tile col stats -> pmax/psum, S~ fp16  [scores]
template <int ASRC, int EPI>
__global__ void __launch_bounds__(256, 2) gemm_f16(
    const _Float16* __restrict__ Ap, long lda, long zsa,
    const _Float16* __restrict__ Bp, long ldb, long zsb,
    int kslice,
    const _Float16* __restrict__ fs16, long zsl,
    float* __restrict__ outF, _Float16* __restrict__ outH, long ldc, long zso,
    const float* __restrict__ bias0, const float* __restrict__ bias1,
    const float* __restrict__ xadd,
    float* __restrict__ pmax, float* __restrict__ psum, long zsp,
    float alpha)
{
  __shared__ _Float16 smem[8192];  // 16 KB: A tile [0,4096), B tile [4096,8192)
  _Float16* sA = smem;
  _Float16* sB = smem + 4096;

  const int z = blockIdx.z;
  const long i0 = (long)blockIdx.x * 128;
  const long j0 = (long)blockIdx.y * 128;
  const int t = (int)threadIdx.x;
  const int lane = t & 63;
  const int wv = t >> 6;
  const int quad = lane >> 4;
  const int lrow = lane & 15;
  const int wm = (wv & 1) << 6;
  const int wn = (wv >> 1) << 6;

  // DMA staging: wave wv stages 16-row slabs {2wv, 2wv+1} of both tiles.
  // Slab = 16 rows x 32 f16 = 1024 B; lane l -> row l>>2, kseg l&3 (LDS contiguous).
  const int idx0 = wv * 2;
  const int srow = lane >> 2;
  const int sseg = (lane & 3) << 3;
  const _Float16* gA0 = Ap + z * zsa + (i0 + idx0 * 16 + srow) * lda + sseg;
  const _Float16* gA1 = gA0 + 16 * lda;
  const _Float16* gB0 = Bp + z * zsb + (j0 + idx0 * 16 + srow) * ldb + sseg;
  const _Float16* gB1 = gB0 + 16 * ldb;
  _Float16* lA0 = sA + idx0 * 512;
  _Float16* lA1 = lA0 + 512;
  _Float16* lB0 = sB + idx0 * 512;
  _Float16* lB1 = lB0 + 512;

  const _Float16* fsZ = nullptr;
  if constexpr (ASRC == 1)
    fsZ = fs16 + z * zsl + (long)blockIdx.x * 4096 + quad * 8;

  f32x4 acc[4][4];
  const f32x4 fz = {0.f, 0.f, 0.f, 0.f};
#pragma unroll
  for (int a = 0; a < 4; a++)
#pragma unroll
    for (int b = 0; b < 4; b++) acc[a][b] = fz;

  for (int kk = 0; kk < kslice; kk += 32) {
    __syncthreads();  // all waves done reading previous tile
    dma16(gA0 + kk, lA0);
    dma16(gA1 + kk, lA1);
    dma16(gB0 + kk, lB0);
    dma16(gB1 + kk, lB1);
    __syncthreads();  // compiler drains vmcnt(0): DMA data visible

    f16x8 fa[4], fb[4];
#pragma unroll
    for (int f = 0; f < 4; f++) {
      fa[f] = *(const f16x8*)&sA[(wm + f * 16 + lrow) * 32 + quad * 8];
      fb[f] = *(const f16x8*)&sB[(wn + f * 16 + lrow) * 32 + quad * 8];
    }
    if constexpr (ASRC == 1) {
      const f16x8 fsv = *(const f16x8*)(fsZ + kk);  // per-k scale, same for all rows
#pragma unroll
      for (int f = 0; f < 4; f++) fa[f] = fa[f] * fsv;
    }
#pragma unroll
    for (int fm = 0; fm < 4; fm++)
#pragma unroll
      for (int fn = 0; fn < 4; fn++)
        acc[fm][fn] = __builtin_amdgcn_mfma_f32_16x16x32_f16(fa[fm], fb[fn], acc[fm][fn], 0, 0, 0);
  }

  // D frag: col(j) = lane&15 (+wn+fn*16), row(i) = quad*4 + reg (+wm+fm*16)
  const long obase = (long)z * zso;

  if constexpr (EPI == 1 || EPI == 2) {
#pragma unroll
    for (int fm = 0; fm < 4; fm++) {
      const long gi0 = i0 + wm + fm * 16 + quad * 4;
#pragma unroll
      for (int fn = 0; fn < 4; fn++) {
        const long gj = j0 + wn + fn * 16 + lrow;
        float badd = 0.f;
        if constexpr (EPI == 1) badd = (gj < 512) ? bias0[gj] : bias1[gj - 512];
#pragma unroll
        for (int r = 0; r < 4; r++) {
          float v = acc[fm][fn][r];
          if constexpr (EPI == 1) v += badd;
          else v += bias0[gi0 + r];
          outH[obase + (gi0 + r) * ldc + gj] = (_Float16)v;
        }
      }
    }
  } else if constexpr (EPI == 3) {
#pragma unroll
    for (int fm = 0; fm < 4; fm++) {
      const long gi0 = i0 + wm + fm * 16 + quad * 4;
#pragma unroll
      for (int fn = 0; fn < 4; fn++) {
        const long gj = j0 + wn + fn * 16 + lrow;
#pragma unroll
        for (int r = 0; r < 4; r++) {
          const long o = obase + (gi0 + r) * ldc + gj;
          outF[o] = fmaf(alpha, acc[fm][fn][r], xadd[o]);
        }
      }
    }
  } else {  // EPI == 4: fused scores stats + S~ store
    __syncthreads();  // done with K-loop LDS
    float* Ls = (float*)smem;  // 2560 floats scratch (10 KB <= 16 KB)
    // stage 1: per-lane per-column-group stats (16 rows each)
#pragma unroll
    for (int fn = 0; fn < 4; fn++) {
      float mx = -3.4e38f;
#pragma unroll
      for (int fm = 0; fm < 4; fm++)
#pragma unroll
        for (int r = 0; r < 4; r++) mx = fmaxf(mx, acc[fm][fn][r]);
      float sm = 0.f;
#pragma unroll
      for (int fm = 0; fm < 4; fm++)
#pragma unroll
        for (int r = 0; r < 4; r++) sm += __expf(acc[fm][fn][r] - mx);
      Ls[(wv * 4 + quad) * 64 + fn * 16 + lrow] = mx;
      Ls[1024 + (wv * 4 + quad) * 64 + fn * 16 + lrow] = sm;
    }
    __syncthreads();
    // stage 2: combine 4 quads -> per (row-half h, col c)
    {
      const int c = t & 127;
      const int h = t >> 7;
      const int wvv = ((c >> 6) << 1) + h;
      const int wc = c & 63;
      float M = -3.4e38f, Ss = 0.f;
#pragma unroll
      for (int q = 0; q < 4; q++) {
        float m2 = Ls[(wvv * 4 + q) * 64 + wc];
        float s2 = Ls[1024 + (wvv * 4 + q) * 64 + wc];
        float nm = fmaxf(M, m2);
        Ss = Ss * __expf(M - nm) + s2 * __expf(m2 - nm);
        M = nm;
      }
      Ls[2048 + h * 128 + c] = M;
      Ls[2304 + h * 128 + c] = Ss;
    }
    __syncthreads();
    // stage 3: combine halves -> per-column tile stats
    if (t < 128) {
      float m0 = Ls[2048 + t], m1 = Ls[2048 + 128 + t];
      float sa = Ls[2304 + t], sb = Ls[2304 + 128 + t];
      float nm = fmaxf(m0, m1);
      float s = sa * __expf(m0 - nm) + sb * __expf(m1 - nm);
      const long pidx = z * zsp + (long)blockIdx.x * 4096 + j0 + t;
      pmax[pidx] = nm;
      psum[pidx] = s;
      Ls[t] = nm;
    }
    __syncthreads();
    // stage 4: store S~ = fp16 exp(acc - tile_col_max)
#pragma unroll
    for (int fn = 0; fn < 4; fn++) {
      const int colc = wn + fn * 16 + lrow;
      const float Mcol = Ls[colc];
      const long gj = j0 + colc;
#pragma unroll
      for (int fm = 0; fm < 4; fm++) {
        const long gi0 = i0 + wm + fm * 16 + quad * 4;
#pragma unroll
        for (int r = 0; r < 4; r++)
          outH[obase + (gi0 + r) * ldc + gj] = (_Float16)__expf(acc[fm][fn][r] - Mcol);
      }
    }
  }
}

__global__ void convert_weights(const float* __restrict__ Wq, const float* __restrict__ Wk,
                                const float* __restrict__ Wv,
                                _Float16* __restrict__ WQK, _Float16* __restrict__ Wv16)
{
  int idx = blockIdx.x * 256 + threadIdx.x;  // 0..786431
  if (idx < 524288)
    WQK[idx] = (_Float16)((idx < 262144) ? Wq[idx] : Wk[idx - 262144]);
  else
    Wv16[idx - 524288] = (_Float16)Wv[idx - 524288];
}

// x [b][c][n] fp32 -> xT [b][n][c] fp16
__global__ void transpose_x(const float* __restrict__ x, _Float16* __restrict__ xT)
{
  __shared__ float tile[32][33];
  const int b = blockIdx.z;
  const int n0 = blockIdx.x * 32;
  const int c0 = blockIdx.y * 32;
  const int tx = threadIdx.x;
  const int ty = threadIdx.y;
  const float* xb = x + (long)b * 2097152;
#pragma unroll
  for (int k = 0; k < 4; k++)
    tile[ty + k * 8][tx] = xb[(long)(c0 + ty + k * 8) * 4096 + n0 + tx];
  __syncthreads();
  _Float16* xTb = xT + (long)b * 2097152;
#pragma unroll
  for (int k = 0; k < 4; k++)
    xTb[(long)(n0 + ty + k * 8) * 512 + c0 + tx] = (_Float16)tile[tx][ty + k * 8];
}

// lse[z][m] = combine 32 tile partials
__global__ void stats_final(const float* __restrict__ pmax, const float* __restrict__ psum,
                            float* __restrict__ lse)
{
  const int idx = blockIdx.x * 256 + threadIdx.x;  // grid 64
  const int z = idx >> 12;
  const int m = idx & 4095;
  const float* pm = pmax + (long)z * 131072 + m;
  const float* ps = psum + (long)z * 131072 + m;
  float M = -3.4e38f, S = 0.f;
  for (int i = 0; i < 32; i++) {
    float m2 = pm[(long)i * 4096], s2 = ps[(long)i * 4096];
    float nm = fmaxf(M, m2);
    S = S * __expf(M - nm) + s2 * __expf(m2 - nm);
    M = nm;
  }
  lse[idx] = M + __logf(S);
}

// fs16[z][tile][m] = fp16 exp(pmax - lse[z][m])
__global__ void scale_factors(const float* __restrict__ pmax, const float* __restrict__ lse,
                              _Float16* __restrict__ fs16)
{
  const int idx = blockIdx.x * 256 + threadIdx.x;  // 0..524287, grid 2048
  const int z = idx >> 17;
  const int m = idx & 4095;
  fs16[idx] = (_Float16)__expf(pmax[idx] - lse[(z << 12) + m]);
}

extern "C" void kernel_launch(void* const* d_in, const int* in_sizes, int n_in,
                              void* d_out, int out_size, void* d_ws, size_t ws_size,
                              hipStream_t stream)
{
  const float* x  = (const float*)d_in[0];
  const float* Wq = (const float*)d_in[1];
  const float* bq = (const float*)d_in[2];
  const float* Wk = (const float*)d_in[3];
  const float* bk = (const float*)d_in[4];
  const float* Wv = (const float*)d_in[5];
  const float* bv = (const float*)d_in[6];
  float* out = (float*)d_out;

  char* w = (char*)d_ws;
  _Float16* WQK   = (_Float16*)(w + 0);          //  1,048,576
  _Float16* Wv16  = (_Float16*)(w + 1048576);    //    524,288
  _Float16* xT    = (_Float16*)(w + 1572864);    // 16,777,216
  _Float16* QK    = (_Float16*)(w + 18350080);   // 33,554,432
  _Float16* Vt    = (_Float16*)(w + 51904512);   // 16,777,216
  float*    lse   = (float*)   (w + 68681728);   //     65,536
  float*    pmaxB = (float*)   (w + 68747264);   //  2,097,152
  float*    psumB = (float*)   (w + 70844416);   //  2,097,152
  _Float16* fs16  = (_Float16*)(w + 72941568);   //  1,048,576 = [z][32][4096] fp16
  _Float16* S16   = (_Float16*)(w + 75038720);   // 134,217,728
  // total 209,256,448 B

  convert_weights<<<3072, 256, 0, stream>>>(Wq, Wk, Wv, WQK, Wv16);
  transpose_x<<<dim3(128, 16, 4), dim3(32, 8), 0, stream>>>(x, xT);

  // projQK: QK[z][n][j] fp16, j<512 Q(+bq), j>=512 K(+bk)
  gemm_f16<0, 1><<<dim3(32, 8, 4), 256, 0, stream>>>(
      xT, 512, 2097152L, WQK, 512, 0L, 512, nullptr, 0L,
      nullptr, QK, 1024, 4194304L, bq, bk, nullptr, nullptr, nullptr, 0L, 0.f);
  // projV: Vt[z][c][m] fp16 (+bv by row)
  gemm_f16<0, 2><<<dim3(4, 32, 4), 256, 0, stream>>>(
      Wv16, 512, 0L, xT, 512, 2097152L, 512, nullptr, 0L,
      nullptr, Vt, 4096, 2097152L, bv, nullptr, nullptr, nullptr, nullptr, 0L, 0.f);
  // scores: S~[z][n][m] fp16 + tile stats
  gemm_f16<0, 4><<<dim3(32, 32, 4), 256, 0, stream>>>(
      QK, 1024, 4194304L, QK + 512, 1024, 4194304L, 512, nullptr, 0L,
      nullptr, S16, 4096, 16777216L, nullptr, nullptr, nullptr,
      pmaxB, psumB, 131072L, 0.f);
  stats_final<<<64, 256, 0, stream>>>(pmaxB, psumB, lse);
  scale_factors<<<2048, 256, 0, stream>>>(pmaxB, lse, fs16);
  // gemm3: out = x.flat + 0.1 * (S~*fs16) · Vt^T   (fs16 z-stride = 131072 elems)
  gemm_f16<1, 3><<<dim3(32, 4, 4), 256, 0, stream>>>(
      S16, 4096, 16777216L, Vt, 4096, 2097152L, 4096, fs16, 131072L,
      out, nullptr, 512, 2097152L, nullptr, nullptr, x, nullptr, nullptr, 0L, 0.1f);
}

// Round 5
// 313.957 us; speedup vs baseline: 1.2148x; 1.2148x over previous
//
#include <hip/hip_runtime.h>
#include <stdint.h>

// ---------------------------------------------------------------------------
// SelfAttention (B=4, C=512, N=4096, A=512), softmax over QUERY axis (n).
// All-fp16 MFMA pipeline, z-batched, register-staged LDS (round-3 structure,
// proven 537 TF on gemm3) with BK=64: two 128x32 K-subtiles per barrier pair
// (8 global loads in flight, 32 MFMA per iteration, half the barrier drains).
//   prep:   weights -> fp16; x[b][c][n] -> xT[b][n][c] fp16
//   projQK: QK[z][n][0:512]=Q+bq, [512:1024]=K+bk          (fp16)
//   projV:  Vt[z][c][m] = Wv·x + bv                         (fp16)
//   scores: S~[z][n][m] = fp16 exp(s - tile_max) + per-tile col stats
//   stats_final -> lse[z][m]; scale_factors -> fs16[z][tile][m] (fp16)
//   gemm3:  out[z][n][c] = x.flat + 0.1 * sum_m (S~*fs16)[n][m] Vt[c][m]
//           (fs16 applied during staging: per-k scale, fp16 pk_mul)
// ---------------------------------------------------------------------------

#define LDT 40    // padded LDS row (f16 elems) per 32-k subtile; proven conflict-OK
#define SUB 5120  // 128*LDT elems per subtile

typedef _Float16 f16x8 __attribute__((ext_vector_type(8)));
typedef float f32x4 __attribute__((ext_vector_type(4)));

// ASRC: 0 = plain A; 1 = A scaled during staging by fs16[z][i0>>7][k] (gemm3)
// EPI:  1 = fp16 out + bias by col (bias0 j<512, bias1 else)  [projQK]
//       2 = fp16 out + bias by row (bias0)                     [projV]
//       3 = fp32 out = xadd[o] + alpha*acc                     [gemm3]
//       4 = fused scores: tile col stats -> pmax/psum, S~ fp16  [scores]
template <int ASRC, int EPI>
__global__ void __launch_bounds__(256, 2) gemm_f16(
    const _Float16* __restrict__ Ap, long lda, long zsa,
    const _Float16* __restrict__ Bp, long ldb, long zsb,
    int kslice,
    const _Float16* __restrict__ fs16, long zsl,
    float* __restrict__ outF, _Float16* __restrict__ outH, long ldc, long zso,
    const float* __restrict__ bias0, const float* __restrict__ bias1,
    const float* __restrict__ xadd,
    float* __restrict__ pmax, float* __restrict__ psum, long zsp,
    float alpha)
{
  __shared__ _Float16 smem[4 * SUB];  // A0 A1 B0 B1, 40 KB
  _Float16* sA0 = smem;
  _Float16* sA1 = smem + SUB;
  _Float16* sB0 = smem + 2 * SUB;
  _Float16* sB1 = smem + 3 * SUB;

  const int z = blockIdx.z;
  const long i0 = (long)blockIdx.x * 128;
  const long j0 = (long)blockIdx.y * 128;
  const int t = (int)threadIdx.x;
  const int lane = t & 63;
  const int wv = t >> 6;
  const int quad = lane >> 4;
  const int lrow = lane & 15;
  const int wm = (wv & 1) << 6;
  const int wn = (wv >> 1) << 6;

  // staging (per 32-k subtile): thread t covers rows r0 and r0+64, k-seg s0
  const int r0 = t >> 2;
  const int s0 = (t & 3) << 3;

  const _Float16* gA0 = Ap + z * zsa + (i0 + r0) * lda + s0;
  const _Float16* gA1 = gA0 + 64 * lda;
  const _Float16* gB0 = Bp + z * zsb + (j0 + r0) * ldb + s0;
  const _Float16* gB1 = gB0 + 64 * ldb;
  const int la0 = r0 * LDT + s0;
  const int la1 = (r0 + 64) * LDT + s0;

  const _Float16* fsZ = nullptr;
  if constexpr (ASRC == 1)
    fsZ = fs16 + z * zsl + (long)blockIdx.x * 4096 + s0;

  f32x4 acc[4][4];
  const f32x4 fz = {0.f, 0.f, 0.f, 0.f};
#pragma unroll
  for (int a = 0; a < 4; a++)
#pragma unroll
    for (int b = 0; b < 4; b++) acc[a][b] = fz;

  for (int kk = 0; kk < kslice; kk += 64) {
    // 8 loads batched in flight; overlap previous iteration's MFMA
    f16x8 va0 = *(const f16x8*)(gA0 + kk);
    f16x8 va1 = *(const f16x8*)(gA1 + kk);
    f16x8 va2 = *(const f16x8*)(gA0 + kk + 32);
    f16x8 va3 = *(const f16x8*)(gA1 + kk + 32);
    f16x8 vb0 = *(const f16x8*)(gB0 + kk);
    f16x8 vb1 = *(const f16x8*)(gB1 + kk);
    f16x8 vb2 = *(const f16x8*)(gB0 + kk + 32);
    f16x8 vb3 = *(const f16x8*)(gB1 + kk + 32);
    if constexpr (ASRC == 1) {
      const f16x8 fsv0 = *(const f16x8*)(fsZ + kk);
      const f16x8 fsv1 = *(const f16x8*)(fsZ + kk + 32);
      va0 = va0 * fsv0;
      va1 = va1 * fsv0;
      va2 = va2 * fsv1;
      va3 = va3 * fsv1;
    }
    __syncthreads();  // all waves done reading previous tiles
    *(f16x8*)&sA0[la0] = va0;
    *(f16x8*)&sA0[la1] = va1;
    *(f16x8*)&sA1[la0] = va2;
    *(f16x8*)&sA1[la1] = va3;
    *(f16x8*)&sB0[la0] = vb0;
    *(f16x8*)&sB0[la1] = vb1;
    *(f16x8*)&sB1[la0] = vb2;
    *(f16x8*)&sB1[la1] = vb3;
    __syncthreads();

#pragma unroll
    for (int h = 0; h < 2; h++) {
      const _Float16* pA = h ? sA1 : sA0;
      const _Float16* pB = h ? sB1 : sB0;
      f16x8 fa[4], fb[4];
#pragma unroll
      for (int f = 0; f < 4; f++) {
        fa[f] = *(const f16x8*)&pA[(wm + f * 16 + lrow) * LDT + quad * 8];
        fb[f] = *(const f16x8*)&pB[(wn + f * 16 + lrow) * LDT + quad * 8];
      }
#pragma unroll
      for (int fm = 0; fm < 4; fm++)
#pragma unroll
        for (int fn = 0; fn < 4; fn++)
          acc[fm][fn] = __builtin_amdgcn_mfma_f32_16x16x32_f16(fa[fm], fb[fn], acc[fm][fn], 0, 0, 0);
    }
  }

  // D frag: col(j) = lane&15 (+wn+fn*16), row(i) = quad*4 + reg (+wm+fm*16)
  const long obase = (long)z * zso;

  if constexpr (EPI == 1 || EPI == 2) {
#pragma unroll
    for (int fm = 0; fm < 4; fm++) {
      const long gi0 = i0 + wm + fm * 16 + quad * 4;
#pragma unroll
      for (int fn = 0; fn < 4; fn++) {
        const long gj = j0 + wn + fn * 16 + lrow;
        float badd = 0.f;
        if constexpr (EPI == 1) badd = (gj < 512) ? bias0[gj] : bias1[gj - 512];
#pragma unroll
        for (int r = 0; r < 4; r++) {
          float v = acc[fm][fn][r];
          if constexpr (EPI == 1) v += badd;
          else v += bias0[gi0 + r];
          outH[obase + (gi0 + r) * ldc + gj] = (_Float16)v;
        }
      }
    }
  } else if constexpr (EPI == 3) {
#pragma unroll
    for (int fm = 0; fm < 4; fm++) {
      const long gi0 = i0 + wm + fm * 16 + quad * 4;
#pragma unroll
      for (int fn = 0; fn < 4; fn++) {
        const long gj = j0 + wn + fn * 16 + lrow;
#pragma unroll
        for (int r = 0; r < 4; r++) {
          const long o = obase + (gi0 + r) * ldc + gj;
          outF[o] = fmaf(alpha, acc[fm][fn][r], xadd[o]);
        }
      }
    }
  } else {  // EPI == 4: fused scores stats + S~ store
    __syncthreads();  // done with K-loop LDS
    float* Ls = (float*)smem;  // 2560 floats scratch
    // stage 1: per-lane per-column-group stats (16 rows each)
#pragma unroll
    for (int fn = 0; fn < 4; fn++) {
      float mx = -3.4e38f;
#pragma unroll
      for (int fm = 0; fm < 4; fm++)
#pragma unroll
        for (int r = 0; r < 4; r++) mx = fmaxf(mx, acc[fm][fn][r]);
      float sm = 0.f;
#pragma unroll
      for (int fm = 0; fm < 4; fm++)
#pragma unroll
        for (int r = 0; r < 4; r++) sm += __expf(acc[fm][fn][r] - mx);
      Ls[(wv * 4 + quad) * 64 + fn * 16 + lrow] = mx;
      Ls[1024 + (wv * 4 + quad) * 64 + fn * 16 + lrow] = sm;
    }
    __syncthreads();
    // stage 2: combine 4 quads -> per (row-half h, col c)
    {
      const int c = t & 127;
      const int h = t >> 7;
      const int wvv = ((c >> 6) << 1) + h;
      const int wc = c & 63;
      float M = -3.4e38f, Ss = 0.f;
#pragma unroll
      for (int q = 0; q < 4; q++) {
        float m2 = Ls[(wvv * 4 + q) * 64 + wc];
        float s2 = Ls[1024 + (wvv * 4 + q) * 64 + wc];
        float nm = fmaxf(M, m2);
        Ss = Ss * __expf(M - nm) + s2 * __expf(m2 - nm);
        M = nm;
      }
      Ls[2048 + h * 128 + c] = M;
      Ls[2304 + h * 128 + c] = Ss;
    }
    __syncthreads();
    // stage 3: combine halves -> per-column tile stats
    if (t < 128) {
      float m0 = Ls[2048 + t], m1 = Ls[2048 + 128 + t];
      float sa = Ls[2304 + t], sb = Ls[2304 + 128 + t];
      float nm = fmaxf(m0, m1);
      float s = sa * __expf(m0 - nm) + sb * __expf(m1 - nm);
      const long pidx = z * zsp + (long)blockIdx.x * 4096 + j0 + t;
      pmax[pidx] = nm;
      psum[pidx] = s;
      Ls[t] = nm;
    }
    __syncthreads();
    // stage 4: store S~ = fp16 exp(acc - tile_col_max)
#pragma unroll
    for (int fn = 0; fn < 4; fn++) {
      const int colc = wn + fn * 16 + lrow;
      const float Mcol = Ls[colc];
      const long gj = j0 + colc;
#pragma unroll
      for (int fm = 0; fm < 4; fm++) {
        const long gi0 = i0 + wm + fm * 16 + quad * 4;
#pragma unroll
        for (int r = 0; r < 4; r++)
          outH[obase + (gi0 + r) * ldc + gj] = (_Float16)__expf(acc[fm][fn][r] - Mcol);
      }
    }
  }
}

__global__ void convert_weights(const float* __restrict__ Wq, const float* __restrict__ Wk,
                                const float* __restrict__ Wv,
                                _Float16* __restrict__ WQK, _Float16* __restrict__ Wv16)
{
  int idx = blockIdx.x * 256 + threadIdx.x;  // 0..786431
  if (idx < 524288)
    WQK[idx] = (_Float16)((idx < 262144) ? Wq[idx] : Wk[idx - 262144]);
  else
    Wv16[idx - 524288] = (_Float16)Wv[idx - 524288];
}

// x [b][c][n] fp32 -> xT [b][n][c] fp16
__global__ void transpose_x(const float* __restrict__ x, _Float16* __restrict__ xT)
{
  __shared__ float tile[32][33];
  const int b = blockIdx.z;
  const int n0 = blockIdx.x * 32;
  const int c0 = blockIdx.y * 32;
  const int tx = threadIdx.x;
  const int ty = threadIdx.y;
  const float* xb = x + (long)b * 2097152;
#pragma unroll
  for (int k = 0; k < 4; k++)
    tile[ty + k * 8][tx] = xb[(long)(c0 + ty + k * 8) * 4096 + n0 + tx];
  __syncthreads();
  _Float16* xTb = xT + (long)b * 2097152;
#pragma unroll
  for (int k = 0; k < 4; k++)
    xTb[(long)(n0 + ty + k * 8) * 512 + c0 + tx] = (_Float16)tile[tx][ty + k * 8];
}

// lse[z][m] = combine 32 tile partials
__global__ void stats_final(const float* __restrict__ pmax, const float* __restrict__ psum,
                            float* __restrict__ lse)
{
  const int idx = blockIdx.x * 256 + threadIdx.x;  // grid 64
  const int z = idx >> 12;
  const int m = idx & 4095;
  const float* pm = pmax + (long)z * 131072 + m;
  const float* ps = psum + (long)z * 131072 + m;
  float M = -3.4e38f, S = 0.f;
  for (int i = 0; i < 32; i++) {
    float m2 = pm[(long)i * 4096], s2 = ps[(long)i * 4096];
    float nm = fmaxf(M, m2);
    S = S * __expf(M - nm) + s2 * __expf(m2 - nm);
    M = nm;
  }
  lse[idx] = M + __logf(S);
}

// fs16[z][tile][m] = fp16 exp(pmax - lse[z][m])
__global__ void scale_factors(const float* __restrict__ pmax, const float* __restrict__ lse,
                              _Float16* __restrict__ fs16)
{
  const int idx = blockIdx.x * 256 + threadIdx.x;  // 0..524287, grid 2048
  const int z = idx >> 17;
  const int m = idx & 4095;
  fs16[idx] = (_Float16)__expf(pmax[idx] - lse[(z << 12) + m]);
}

extern "C" void kernel_launch(void* const* d_in, const int* in_sizes, int n_in,
                              void* d_out, int out_size, void* d_ws, size_t ws_size,
                              hipStream_t stream)
{
  const float* x  = (const float*)d_in[0];
  const float* Wq = (const float*)d_in[1];
  const float* bq = (const float*)d_in[2];
  const float* Wk = (const float*)d_in[3];
  const float* bk = (const float*)d_in[4];
  const float* Wv = (const float*)d_in[5];
  const float* bv = (const float*)d_in[6];
  float* out = (float*)d_out;

  char* w = (char*)d_ws;
  _Float16* WQK   = (_Float16*)(w + 0);          //  1,048,576
  _Float16* Wv16  = (_Float16*)(w + 1048576);    //    524,288
  _Float16* xT    = (_Float16*)(w + 1572864);    // 16,777,216
  _Float16* QK    = (_Float16*)(w + 18350080);   // 33,554,432
  _Float16* Vt    = (_Float16*)(w + 51904512);   // 16,777,216
  float*    lse   = (float*)   (w + 68681728);   //     65,536
  float*    pmaxB = (float*)   (w + 68747264);   //  2,097,152
  float*    psumB = (float*)   (w + 70844416);   //  2,097,152
  _Float16* fs16  = (_Float16*)(w + 72941568);   //  1,048,576 = [z][32][4096] fp16
  _Float16* S16   = (_Float16*)(w + 75038720);   // 134,217,728
  // total 209,256,448 B

  convert_weights<<<3072, 256, 0, stream>>>(Wq, Wk, Wv, WQK, Wv16);
  transpose_x<<<dim3(128, 16, 4), dim3(32, 8), 0, stream>>>(x, xT);

  // projQK: QK[z][n][j] fp16, j<512 Q(+bq), j>=512 K(+bk)
  gemm_f16<0, 1><<<dim3(32, 8, 4), 256, 0, stream>>>(
      xT, 512, 2097152L, WQK, 512, 0L, 512, nullptr, 0L,
      nullptr, QK, 1024, 4194304L, bq, bk, nullptr, nullptr, nullptr, 0L, 0.f);
  // projV: Vt[z][c][m] fp16 (+bv by row)
  gemm_f16<0, 2><<<dim3(4, 32, 4), 256, 0, stream>>>(
      Wv16, 512, 0L, xT, 512, 2097152L, 512, nullptr, 0L,
      nullptr, Vt, 4096, 2097152L, bv, nullptr, nullptr, nullptr, nullptr, 0L, 0.f);
  // scores: S~[z][n][m] fp16 + tile stats
  gemm_f16<0, 4><<<dim3(32, 32, 4), 256, 0, stream>>>(
      QK, 1024, 4194304L, QK + 512, 1024, 4194304L, 512, nullptr, 0L,
      nullptr, S16, 4096, 16777216L, nullptr, nullptr, nullptr,
      pmaxB, psumB, 131072L, 0.f);
  stats_final<<<64, 256, 0, stream>>>(pmaxB, psumB, lse);
  scale_factors<<<2048, 256, 0, stream>>>(pmaxB, lse, fs16);
  // gemm3: out = x.flat + 0.1 * (S~*fs16) · Vt^T   (fs16 z-stride = 131072 elems)
  gemm_f16<1, 3><<<dim3(32, 4, 4), 256, 0, stream>>>(
      S16, 4096, 16777216L, Vt, 4096, 2097152L, 4096, fs16, 131072L,
      out, nullptr, 512, 2097152L, nullptr, nullptr, x, nullptr, nullptr, 0L, 0.1f);
}

// Round 6
// 311.358 us; speedup vs baseline: 1.2249x; 1.0083x over previous
//
#include <hip/hip_runtime.h>
#include <stdint.h>

// ---------------------------------------------------------------------------
// SelfAttention (B=4, C=512, N=4096, A=512), softmax over QUERY axis (n).
// All-fp16 MFMA pipeline, z-batched, register-staged LDS, NSUB 32-k subtiles
// per barrier pair (NSUB=2 for most GEMMs; NSUB=4 for gemm3, which is
// grid-capped at 2 blocks/CU so 80 KB LDS costs no occupancy).
//   prep:   weights -> fp16; x[b][c][n] -> xT[b][n][c] fp16
//   projQK: QK[z][n][0:512]=Q+bq, [512:1024]=K+bk          (fp16)
//   projV:  Vt[z][c][m] = Wv·x + bv                         (fp16)
//   scores: S~[z][n][m] = fp16 exp(s - tile_col_max), tile col max/sum stats
//           (single-exp epilogue: max-reduce first, then one exp pass that
//            feeds both the S~ store and the column sum)
//   stats_scale: lse + fs16[z][tile][m] = fp16 exp(pmax - lse)  (fused)
//   gemm3:  out[z][n][c] = x.flat + 0.1 * sum_m (S~*fs16)[n][m] Vt[c][m]
// ---------------------------------------------------------------------------

#define LDT 40    // padded LDS row (f16 elems) per 32-k subtile
#define SUB 5120  // 128*LDT elems per subtile

typedef _Float16 f16x8 __attribute__((ext_vector_type(8)));
typedef float f32x4 __attribute__((ext_vector_type(4)));

// ASRC: 0 = plain A; 1 = A scaled during staging by fs16[z][i0>>7][k] (gemm3)
// EPI:  1 = fp16 out + bias by col (bias0 j<512, bias1 else)  [projQK]
//       2 = fp16 out + bias by row (bias0)                     [projV]
//       3 = fp32 out = xadd[o] + alpha*acc                     [gemm3]
//       4 = fused scores: tile col stats -> pmax/psum, S~ fp16  [scores]
template <int ASRC, int EPI, int NSUB>
__global__ void __launch_bounds__(256, 2) gemm_f16(
    const _Float16* __restrict__ Ap, long lda, long zsa,
    const _Float16* __restrict__ Bp, long ldb, long zsb,
    int kslice,
    const _Float16* __restrict__ fs16, long zsl,
    float* __restrict__ outF, _Float16* __restrict__ outH, long ldc, long zso,
    const float* __restrict__ bias0, const float* __restrict__ bias1,
    const float* __restrict__ xadd,
    float* __restrict__ pmax, float* __restrict__ psum, long zsp,
    float alpha)
{
  __shared__ _Float16 smem[2 * NSUB * SUB];  // A subtiles then B subtiles

  const int z = blockIdx.z;
  const long i0 = (long)blockIdx.x * 128;
  const long j0 = (long)blockIdx.y * 128;
  const int t = (int)threadIdx.x;
  const int lane = t & 63;
  const int wv = t >> 6;
  const int quad = lane >> 4;
  const int lrow = lane & 15;
  const int wm = (wv & 1) << 6;
  const int wn = (wv >> 1) << 6;

  // staging (per 32-k subtile): thread t covers rows r0 and r0+64, k-seg s0
  const int r0 = t >> 2;
  const int s0 = (t & 3) << 3;

  const _Float16* gA0 = Ap + z * zsa + (i0 + r0) * lda + s0;
  const _Float16* gA1 = gA0 + 64 * lda;
  const _Float16* gB0 = Bp + z * zsb + (j0 + r0) * ldb + s0;
  const _Float16* gB1 = gB0 + 64 * ldb;
  const int la0 = r0 * LDT + s0;
  const int la1 = (r0 + 64) * LDT + s0;

  const _Float16* fsZ = nullptr;
  if constexpr (ASRC == 1)
    fsZ = fs16 + z * zsl + (long)blockIdx.x * 4096 + s0;

  f32x4 acc[4][4];
  const f32x4 fz = {0.f, 0.f, 0.f, 0.f};
#pragma unroll
  for (int a = 0; a < 4; a++)
#pragma unroll
    for (int b = 0; b < 4; b++) acc[a][b] = fz;

  for (int kk = 0; kk < kslice; kk += 32 * NSUB) {
    // 8*NSUB loads batched in flight; overlap previous iteration's MFMA
    f16x8 va[NSUB][2], vb[NSUB][2];
#pragma unroll
    for (int s = 0; s < NSUB; s++) {
      va[s][0] = *(const f16x8*)(gA0 + kk + 32 * s);
      va[s][1] = *(const f16x8*)(gA1 + kk + 32 * s);
      vb[s][0] = *(const f16x8*)(gB0 + kk + 32 * s);
      vb[s][1] = *(const f16x8*)(gB1 + kk + 32 * s);
    }
    if constexpr (ASRC == 1) {
#pragma unroll
      for (int s = 0; s < NSUB; s++) {
        const f16x8 fsv = *(const f16x8*)(fsZ + kk + 32 * s);
        va[s][0] = va[s][0] * fsv;
        va[s][1] = va[s][1] * fsv;
      }
    }
    __syncthreads();  // all waves done reading previous tiles
#pragma unroll
    for (int s = 0; s < NSUB; s++) {
      *(f16x8*)&smem[s * SUB + la0] = va[s][0];
      *(f16x8*)&smem[s * SUB + la1] = va[s][1];
      *(f16x8*)&smem[(NSUB + s) * SUB + la0] = vb[s][0];
      *(f16x8*)&smem[(NSUB + s) * SUB + la1] = vb[s][1];
    }
    __syncthreads();

#pragma unroll
    for (int h = 0; h < NSUB; h++) {
      const _Float16* pA = smem + h * SUB;
      const _Float16* pB = smem + (NSUB + h) * SUB;
      f16x8 fa[4], fb[4];
#pragma unroll
      for (int f = 0; f < 4; f++) {
        fa[f] = *(const f16x8*)&pA[(wm + f * 16 + lrow) * LDT + quad * 8];
        fb[f] = *(const f16x8*)&pB[(wn + f * 16 + lrow) * LDT + quad * 8];
      }
#pragma unroll
      for (int fm = 0; fm < 4; fm++)
#pragma unroll
        for (int fn = 0; fn < 4; fn++)
          acc[fm][fn] = __builtin_amdgcn_mfma_f32_16x16x32_f16(fa[fm], fb[fn], acc[fm][fn], 0, 0, 0);
    }
  }

  // D frag: col(j) = lane&15 (+wn+fn*16), row(i) = quad*4 + reg (+wm+fm*16)
  const long obase = (long)z * zso;

  if constexpr (EPI == 1 || EPI == 2) {
#pragma unroll
    for (int fm = 0; fm < 4; fm++) {
      const long gi0 = i0 + wm + fm * 16 + quad * 4;
#pragma unroll
      for (int fn = 0; fn < 4; fn++) {
        const long gj = j0 + wn + fn * 16 + lrow;
        float badd = 0.f;
        if constexpr (EPI == 1) badd = (gj < 512) ? bias0[gj] : bias1[gj - 512];
#pragma unroll
        for (int r = 0; r < 4; r++) {
          float v = acc[fm][fn][r];
          if constexpr (EPI == 1) v += badd;
          else v += bias0[gi0 + r];
          outH[obase + (gi0 + r) * ldc + gj] = (_Float16)v;
        }
      }
    }
  } else if constexpr (EPI == 3) {
#pragma unroll
    for (int fm = 0; fm < 4; fm++) {
      const long gi0 = i0 + wm + fm * 16 + quad * 4;
#pragma unroll
      for (int fn = 0; fn < 4; fn++) {
        const long gj = j0 + wn + fn * 16 + lrow;
#pragma unroll
        for (int r = 0; r < 4; r++) {
          const long o = obase + (gi0 + r) * ldc + gj;
          outF[o] = fmaf(alpha, acc[fm][fn][r], xadd[o]);
        }
      }
    }
  } else {  // EPI == 4: single-exp fused scores epilogue
    __syncthreads();  // done with K-loop LDS
    float* Ls = (float*)smem;
    // LDS float layout: [0,1024) partials (max, then reused for sums)
    //                   [1024,1280) half-maxes, [1280,1408) Mcol
    // stage 1: per-lane per-column-group MAX only (no exp)
#pragma unroll
    for (int fn = 0; fn < 4; fn++) {
      float mx = -3.4e38f;
#pragma unroll
      for (int fm = 0; fm < 4; fm++)
#pragma unroll
        for (int r = 0; r < 4; r++) mx = fmaxf(mx, acc[fm][fn][r]);
      Ls[(wv * 4 + quad) * 64 + fn * 16 + lrow] = mx;
    }
    __syncthreads();
    // stage 2: combine 4 quads -> per (row-half h, col c) max
    {
      const int c = t & 127;
      const int h = t >> 7;
      const int wvv = ((c >> 6) << 1) + h;
      const int wc = c & 63;
      float M = -3.4e38f;
#pragma unroll
      for (int q = 0; q < 4; q++) M = fmaxf(M, Ls[(wvv * 4 + q) * 64 + wc]);
      Ls[1024 + h * 128 + c] = M;
    }
    __syncthreads();
    // stage 3: column max; store pmax; park Mcol in LDS
    if (t < 128) {
      float Mcol = fmaxf(Ls[1024 + t], Ls[1152 + t]);
      pmax[z * zsp + (long)blockIdx.x * 4096 + j0 + t] = Mcol;
      Ls[1280 + t] = Mcol;
    }
    __syncthreads();
    // stage 4: single exp pass — store S~ AND accumulate column partial sums
#pragma unroll
    for (int fn = 0; fn < 4; fn++) {
      const int colc = wn + fn * 16 + lrow;
      const float Mcol = Ls[1280 + colc];
      const long gj = j0 + colc;
      float sm = 0.f;
#pragma unroll
      for (int fm = 0; fm < 4; fm++) {
        const long gi0 = i0 + wm + fm * 16 + quad * 4;
#pragma unroll
        for (int r = 0; r < 4; r++) {
          float e = __expf(acc[fm][fn][r] - Mcol);
          sm += e;
          outH[obase + (gi0 + r) * ldc + gj] = (_Float16)e;
        }
      }
      Ls[(wv * 4 + quad) * 64 + fn * 16 + lrow] = sm;  // reuse partial region
    }
    __syncthreads();
    // stage 5: pure-add reduce of 8 partials per column -> psum
    if (t < 128) {
      const int wc = t & 63;
      const int ch = t >> 6;
      float s = 0.f;
#pragma unroll
      for (int h = 0; h < 2; h++) {
        const int wvv = (ch << 1) + h;
#pragma unroll
        for (int q = 0; q < 4; q++) s += Ls[(wvv * 4 + q) * 64 + wc];
      }
      psum[z * zsp + (long)blockIdx.x * 4096 + j0 + t] = s;
    }
  }
}

__global__ void convert_weights(const float* __restrict__ Wq, const float* __restrict__ Wk,
                                const float* __restrict__ Wv,
                                _Float16* __restrict__ WQK, _Float16* __restrict__ Wv16)
{
  int idx = blockIdx.x * 256 + threadIdx.x;  // 0..786431
  if (idx < 524288)
    WQK[idx] = (_Float16)((idx < 262144) ? Wq[idx] : Wk[idx - 262144]);
  else
    Wv16[idx - 524288] = (_Float16)Wv[idx - 524288];
}

// x [b][c][n] fp32 -> xT [b][n][c] fp16
__global__ void transpose_x(const float* __restrict__ x, _Float16* __restrict__ xT)
{
  __shared__ float tile[32][33];
  const int b = blockIdx.z;
  const int n0 = blockIdx.x * 32;
  const int c0 = blockIdx.y * 32;
  const int tx = threadIdx.x;
  const int ty = threadIdx.y;
  const float* xb = x + (long)b * 2097152;
#pragma unroll
  for (int k = 0; k < 4; k++)
    tile[ty + k * 8][tx] = xb[(long)(c0 + ty + k * 8) * 4096 + n0 + tx];
  __syncthreads();
  _Float16* xTb = xT + (long)b * 2097152;
#pragma unroll
  for (int k = 0; k < 4; k++)
    xTb[(long)(n0 + ty + k * 8) * 512 + c0 + tx] = (_Float16)tile[tx][ty + k * 8];
}

// fused: lse[z][m] from 32 tile partials, then fs16[z][tile][m] = exp(pmax-lse)
__global__ void stats_scale(const float* __restrict__ pmax, const float* __restrict__ psum,
                            _Float16* __restrict__ fs16)
{
  const int idx = blockIdx.x * 256 + threadIdx.x;  // grid 64: z*4096+m
  const int z = idx >> 12;
  const int m = idx & 4095;
  const float* pm = pmax + (long)z * 131072 + m;
  const float* ps = psum + (long)z * 131072 + m;
  float M = -3.4e38f, S = 0.f;
  for (int i = 0; i < 32; i++) {
    float m2 = pm[(long)i * 4096], s2 = ps[(long)i * 4096];
    float nm = fmaxf(M, m2);
    S = S * __expf(M - nm) + s2 * __expf(m2 - nm);
    M = nm;
  }
  const float lse = M + __logf(S);
  _Float16* fo = fs16 + (long)z * 131072 + m;
  for (int i = 0; i < 32; i++)
    fo[(long)i * 4096] = (_Float16)__expf(pm[(long)i * 4096] - lse);
}

extern "C" void kernel_launch(void* const* d_in, const int* in_sizes, int n_in,
                              void* d_out, int out_size, void* d_ws, size_t ws_size,
                              hipStream_t stream)
{
  const float* x  = (const float*)d_in[0];
  const float* Wq = (const float*)d_in[1];
  const float* bq = (const float*)d_in[2];
  const float* Wk = (const float*)d_in[3];
  const float* bk = (const float*)d_in[4];
  const float* Wv = (const float*)d_in[5];
  const float* bv = (const float*)d_in[6];
  float* out = (float*)d_out;

  char* w = (char*)d_ws;
  _Float16* WQK   = (_Float16*)(w + 0);          //  1,048,576
  _Float16* Wv16  = (_Float16*)(w + 1048576);    //    524,288
  _Float16* xT    = (_Float16*)(w + 1572864);    // 16,777,216
  _Float16* QK    = (_Float16*)(w + 18350080);   // 33,554,432
  _Float16* Vt    = (_Float16*)(w + 51904512);   // 16,777,216
  float*    pmaxB = (float*)   (w + 68747264);   //  2,097,152
  float*    psumB = (float*)   (w + 70844416);   //  2,097,152
  _Float16* fs16  = (_Float16*)(w + 72941568);   //  1,048,576 = [z][32][4096] fp16
  _Float16* S16   = (_Float16*)(w + 75038720);   // 134,217,728
  // total 209,256,448 B

  convert_weights<<<3072, 256, 0, stream>>>(Wq, Wk, Wv, WQK, Wv16);
  transpose_x<<<dim3(128, 16, 4), dim3(32, 8), 0, stream>>>(x, xT);

  // projQK: QK[z][n][j] fp16, j<512 Q(+bq), j>=512 K(+bk)
  gemm_f16<0, 1, 2><<<dim3(32, 8, 4), 256, 0, stream>>>(
      xT, 512, 2097152L, WQK, 512, 0L, 512, nullptr, 0L,
      nullptr, QK, 1024, 4194304L, bq, bk, nullptr, nullptr, nullptr, 0L, 0.f);
  // projV: Vt[z][c][m] fp16 (+bv by row)
  gemm_f16<0, 2, 2><<<dim3(4, 32, 4), 256, 0, stream>>>(
      Wv16, 512, 0L, xT, 512, 2097152L, 512, nullptr, 0L,
      nullptr, Vt, 4096, 2097152L, bv, nullptr, nullptr, nullptr, nullptr, 0L, 0.f);
  // scores: S~[z][n][m] fp16 + tile col stats (single-exp epilogue)
  gemm_f16<0, 4, 2><<<dim3(32, 32, 4), 256, 0, stream>>>(
      QK, 1024, 4194304L, QK + 512, 1024, 4194304L, 512, nullptr, 0L,
      nullptr, S16, 4096, 16777216L, nullptr, nullptr, nullptr,
      pmaxB, psumB, 131072L, 0.f);
  stats_scale<<<64, 256, 0, stream>>>(pmaxB, psumB, fs16);
  // gemm3 (NSUB=4: 80 KB LDS, grid-capped 2 blocks/CU anyway):
  // out = x.flat + 0.1 * (S~*fs16) · Vt^T   (fs16 z-stride = 131072 elems)
  gemm_f16<1, 3, 4><<<dim3(32, 4, 4), 256, 0, stream>>>(
      S16, 4096, 16777216L, Vt, 4096, 2097152L, 4096, fs16, 131072L,
      out, nullptr, 512, 2097152L, nullptr, nullptr, x, nullptr, nullptr, 0L, 0.1f);
}